// Round 9
// baseline (928.031 us; speedup 1.0000x reference)
//
#include <hip/hip_runtime.h>
#include <math.h>

typedef __attribute__((ext_vector_type(4))) float f32x4;
typedef __attribute__((ext_vector_type(4))) unsigned int u32x4;
typedef __attribute__((ext_vector_type(8))) unsigned short u16x8;
typedef __attribute__((ext_vector_type(8))) __bf16 bf16x8;
typedef unsigned short ushort_t;

#define H_DIM 2048
#define T_TOK 2048
#define NEXP 16
#define I_DIM 1408
#define I2_DIM 2816
#define IS_DIM 5632
#define MAXROWS 8192

static __device__ __forceinline__ unsigned short f2bf(float f){
  union { float f; unsigned u; } v; v.f = f;
  unsigned r = v.u + 0x7FFFu + ((v.u >> 16) & 1u);
  return (unsigned short)(r >> 16);
}
static __device__ __forceinline__ float bf2f(unsigned short h){
  union { unsigned u; float f; } v; v.u = ((unsigned)h) << 16;
  return v.f;
}
static __device__ __forceinline__ float silu_f(float x){ return x / (1.f + __expf(-x)); }

// async global->LDS, 16B/lane; LDS dest wave-uniform base, HW adds lane*16.
static __device__ __forceinline__ void gld16(const ushort_t* g, ushort_t* l){
  __builtin_amdgcn_global_load_lds(
      (const __attribute__((address_space(1))) unsigned int*)g,
      (__attribute__((address_space(3))) unsigned int*)l, 16, 0, 0);
}

// inline-asm ds_read_b128: opaque to LDS-DMA alias tracking (no forced vmcnt drain).
static __device__ __forceinline__ bf16x8 dsr128(unsigned byte_off){
  u32x4 r;
  asm volatile("ds_read_b128 %0, %1" : "=v"(r) : "v"(byte_off));
  return __builtin_bit_cast(bf16x8, r);
}
static __device__ __forceinline__ unsigned ldsaddr(const ushort_t* p){
  return (unsigned)(size_t)(const __attribute__((address_space(3))) ushort_t*)p;
}

// ---------------- cast x -> bf16 ----------------
__global__ void cast_bf16_k(const float* __restrict__ in, ushort_t* __restrict__ out){
  long i = ((long)blockIdx.x * 256 + threadIdx.x) * 8;
  f32x4 a = *(const f32x4*)&in[i];
  f32x4 b = *(const f32x4*)&in[i + 4];
  union { ushort_t s[8]; u32x4 v; } pk;
  #pragma unroll
  for (int j = 0; j < 4; j++){ pk.s[j] = f2bf(a[j]); pk.s[j+4] = f2bf(b[j]); }
  *(u32x4*)&out[i] = pk.v;
}

// ------- transpose + cast: in[z][K][N] fp32 -> out[z][N][K] bf16, 64x64 tiles ------
__global__ void transpose_cast_k(const float* __restrict__ in, ushort_t* __restrict__ out,
                                 int K, int N){
  long zo = (long)blockIdx.z * K * N;
  in += zo; out += zo;
  __shared__ float tl[64][65];
  int n0 = blockIdx.x * 64, k0 = blockIdx.y * 64;
  int tid = threadIdx.x;           // 256
  int lr = tid >> 2;               // source row (k)
  int lv = (tid & 3) * 4;
  #pragma unroll
  for (int j = 0; j < 4; j++){
    int col = lv + j * 16;
    f32x4 v = *(const f32x4*)&in[(long)(k0 + lr) * N + n0 + col];
    tl[lr][col + 0] = v[0]; tl[lr][col + 1] = v[1];
    tl[lr][col + 2] = v[2]; tl[lr][col + 3] = v[3];
  }
  __syncthreads();
  int nl = tid >> 3;
  int kc = (tid & 7) * 8;
  #pragma unroll
  for (int it = 0; it < 2; it++){
    int n = nl + it * 32;
    union { ushort_t s[8]; u32x4 v; } pk;
    #pragma unroll
    for (int j = 0; j < 8; j++) pk.s[j] = f2bf(tl[kc + j][n]);
    *(u32x4*)&out[(long)(n0 + n) * K + k0 + kc] = pk.v;
  }
}

// ---------------- router ----------------
__global__ void router_k(const float* __restrict__ x, const float* __restrict__ rw,
                         const float* __restrict__ sgw, float* __restrict__ logits,
                         int* __restrict__ counts, int* __restrict__ lists,
                         float* __restrict__ probs, float* __restrict__ sgmul){
  int wid = threadIdx.x >> 6, lane = threadIdx.x & 63;
  int t = blockIdx.x * 4 + wid;
  const float* xr = x + (long)t * H_DIM;
  float acc[17];
  #pragma unroll
  for (int e = 0; e < 17; e++) acc[e] = 0.f;
  for (int h0 = lane * 4; h0 < H_DIM; h0 += 256){
    f32x4 xv = *(const f32x4*)&xr[h0];
    #pragma unroll
    for (int i = 0; i < 4; i++){
      float xs = xv[i];
      const float* wrow = rw + (long)(h0 + i) * NEXP;
      #pragma unroll
      for (int e = 0; e < 16; e++) acc[e] += xs * wrow[e];
      acc[16] += xs * sgw[h0 + i];
    }
  }
  #pragma unroll
  for (int e = 0; e < 17; e++)
    for (int off = 32; off >= 1; off >>= 1)
      acc[e] += __shfl_xor(acc[e], off);
  if (lane == 0){
    float* lo = logits + (long)t * NEXP;
    #pragma unroll
    for (int e = 0; e < 16; e++) lo[e] = acc[e];
    int e0 = 0;
    #pragma unroll
    for (int e = 1; e < 16; e++) if (acc[e] > acc[e0]) e0 = e;
    int e1 = (e0 == 0) ? 1 : 0;
    #pragma unroll
    for (int e = 0; e < 16; e++) if (e != e0 && acc[e] > acc[e1]) e1 = e;
    float d = acc[e1] - acc[e0];
    float ed = __expf(d);
    float p0 = 1.f / (1.f + ed);
    float p1 = ed / (1.f + ed);
    int pos0 = atomicAdd(&counts[e0], 1);
    lists[e0 * T_TOK + pos0] = t; probs[e0 * T_TOK + pos0] = p0;
    int pos1 = atomicAdd(&counts[e1], 1);
    lists[e1 * T_TOK + pos1] = t; probs[e1 * T_TOK + pos1] = p1;
    sgmul[t] = 1.f / (1.f + __expf(-acc[16]));
  }
}

// ---------------- padded prefix bases (256-aligned for 256-row tiles) ----------------
__global__ void bases_k(const int* __restrict__ counts, int* __restrict__ bases){
  if (threadIdx.x == 0){
    int r = 0;
    for (int e = 0; e < NEXP; e++){ bases[e] = r; r += (counts[e] + 255) & ~255; }
  }
}

// ---------------- SwiGLU elementwise ----------------
__global__ void swiglu_expert_k(const ushort_t* __restrict__ gu, ushort_t* __restrict__ hid){
  long qd = (long)blockIdx.x * 256 + threadIdx.x;
  long r = qd / (I_DIM / 8); int ic = (int)(qd % (I_DIM / 8)) * 8;
  const ushort_t* g = gu + r * I2_DIM + ic;
  u16x8 gv = *(const u16x8*)g;
  u16x8 uv = *(const u16x8*)(g + I_DIM);
  u16x8 ov;
  #pragma unroll
  for (int i = 0; i < 8; i++)
    ov[i] = f2bf(bf2f(uv[i]) * silu_f(bf2f(gv[i])));
  *(u16x8*)&hid[r * I_DIM + ic] = ov;
}

__global__ void swiglu_flat_k(ushort_t* __restrict__ sg, const ushort_t* __restrict__ si){
  long i = ((long)blockIdx.x * 256 + threadIdx.x) * 8;
  u16x8 g = *(const u16x8*)&sg[i];
  u16x8 s = *(const u16x8*)&si[i];
  u16x8 o;
  #pragma unroll
  for (int j = 0; j < 8; j++)
    o[j] = f2bf(bf2f(s[j]) * silu_f(bf2f(g[j])));
  *(u16x8*)&sg[i] = o;
}

// ======== 256x256 / BK=32 / 8-wave GEMM; static dual LDS buffers, unroll-2, asm reads ========
// 64 KiB LDS -> 2 blocks/CU. Per body: vmcnt(0) [drains loads issued one full body earlier]
// -> s_barrier -> stage(t+1 -> other buf) -> 12 asm ds_read_b128 -> lgkmcnt(0) -> 32 MFMA.
// One barrier + one (near-free) vmcnt drain per K-tile; prefetch flies across a full body.
template<int MODE>
static __device__ __forceinline__ void gemm4_body(
    const ushort_t* __restrict__ A, const ushort_t* __restrict__ Bt,
    const ushort_t* __restrict__ Bt2, ushort_t* __restrict__ Cb,
    int K, int lda, int ldbt, int ldc, int mb,
    const int* __restrict__ counts, const int* __restrict__ bases,
    const int* __restrict__ lists, const float* __restrict__ probs,
    const float* __restrict__ svec, float* __restrict__ outp, long bstride){
  int z = blockIdx.z;
  int cnt = T_TOK;
  const ushort_t* Ab = A;
  const ushort_t* Bb = Bt;
  long rbase = 0;
  if constexpr (MODE == 0){ if (z){ Bb = Bt2; Cb += (long)T_TOK * ldc; } }
  if constexpr (MODE == 1){ cnt = counts[z]; rbase = bases[z]; Bb += (long)z * bstride; }
  if constexpr (MODE == 2){ cnt = counts[z]; Ab += (long)bases[z] * lda; Bb += (long)z * bstride; }

  int kb = K / gridDim.y;          // MODE 3 K-split; others gridDim.y==1
  int kbase = blockIdx.y * kb;
  Ab += kbase;
  Bb += kbase;                     // Bt is [N][K], k fastest

  // bijective XCD-chunked swizzle (m204); all nwg here are multiples of 8.
  int nwg = gridDim.x;
  int wgo = blockIdx.x;
  int q = nwg >> 3, r = nwg & 7;
  int xcd = wgo & 7, idx = wgo >> 3;
  int wg = (xcd < r ? xcd * (q + 1) : r * (q + 1) + (xcd - r) * q) + idx;
  int m0 = (wg % mb) * 256;
  if (m0 >= cnt) return;
  int n0 = (wg / mb) * 256;

  // static dual buffers: compile-time identity (A0/B0 vs A1/B1)
  __shared__ ushort_t A0[8192], B0[8192], A1[8192], B1[8192];  // 4 x 16 KiB

  int tid = threadIdx.x;
  int lane = tid & 63;
  int wv = tid >> 6;        // 8 waves
  int wm = wv >> 2;         // 0..1 -> 128 rows
  int wn = wv & 3;          // 0..3 -> 64 cols

  // staging: wave wv stages A rows [wv*32,+32) and B rows [wv*32,+32), 2 gld16 each.
  // gld16 covers 16 rows (lane>>2) x 4 slots of 16B (lane&3); source slot pre-swizzled
  // (lane&3)^(row&3) so LDS is linear while reads XOR the same way (involution).
  int srow = lane >> 2;
  int sslot = ((lane & 3) ^ (srow & 3)) * 8;
  long aoff[2], boff[2];
  #pragma unroll
  for (int c = 0; c < 2; c++){
    int mr = wv * 32 + c * 16 + srow;
    int grow;
    if constexpr (MODE == 1){
      int j = m0 + mr; if (j >= cnt) j = cnt - 1;
      grow = lists[z * T_TOK + j];
    } else {
      grow = m0 + mr;
    }
    aoff[c] = (long)grow * lda + sslot;
    boff[c] = (long)(n0 + mr) * ldbt + sslot;
  }

  auto stg = [&](long t, ushort_t* dA, ushort_t* dB){
    long ko = t * 32;
    ushort_t* wA = dA + wv * 1024;
    ushort_t* wB = dB + wv * 1024;
    gld16(Ab + aoff[0] + ko, wA);
    gld16(Ab + aoff[1] + ko, wA + 512);
    gld16(Bb + boff[0] + ko, wB);
    gld16(Bb + boff[1] + ko, wB + 512);
  };

  f32x4 zero = {0.f, 0.f, 0.f, 0.f};
  f32x4 acc[8][4];
  #pragma unroll
  for (int i = 0; i < 8; i++)
    #pragma unroll
    for (int j = 0; j < 4; j++) acc[i][j] = zero;

  // fragment read offsets (bytes): row stride 64 B; slot = ((lane>>4) ^ (lane&3))*16
  unsigned ps = (unsigned)(((lane >> 4) ^ (lane & 3)) << 4);
  unsigned aro = (unsigned)((wm * 128 + (lane & 15)) * 64) + ps;  // + fm*1024
  unsigned bro = (unsigned)((wn * 64 + (lane & 15)) * 64) + ps;   // + fn*1024
  unsigned a0b = ldsaddr(A0), b0b = ldsaddr(B0);
  unsigned a1b = ldsaddr(A1), b1b = ldsaddr(B1);

  int nt = kb >> 5;          // all K values give even nt (64 / 176 / 44)
  stg(0, A0, B0);

  #define BODY(T, CURA, CURB, NXA, NXB)                                          \
  {                                                                              \
    asm volatile("s_waitcnt vmcnt(0)" ::: "memory");                             \
    __builtin_amdgcn_s_barrier();                                                \
    __builtin_amdgcn_sched_barrier(0);                                           \
    if ((T) + 1 < nt) stg((T) + 1, NXA, NXB);                                    \
    __builtin_amdgcn_sched_barrier(0);                                           \
    bf16x8 af[8], bg[4];                                                         \
    _Pragma("unroll")                                                            \
    for (int f = 0; f < 8; f++) af[f] = dsr128(CURA + aro + f * 1024u);          \
    _Pragma("unroll")                                                            \
    for (int f = 0; f < 4; f++) bg[f] = dsr128(CURB + bro + f * 1024u);          \
    asm volatile("s_waitcnt lgkmcnt(0)" ::: "memory");                           \
    __builtin_amdgcn_sched_barrier(0);                                           \
    __builtin_amdgcn_s_setprio(1);                                               \
    _Pragma("unroll")                                                            \
    for (int fm = 0; fm < 8; fm++)                                               \
      _Pragma("unroll")                                                          \
      for (int fn = 0; fn < 4; fn++)                                             \
        acc[fm][fn] = __builtin_amdgcn_mfma_f32_16x16x32_bf16(af[fm], bg[fn],    \
                                                              acc[fm][fn], 0, 0, 0); \
    __builtin_amdgcn_s_setprio(0);                                               \
  }

  for (int t = 0; t < nt; t += 2){
    BODY(t,     a0b, b0b, A1, B1);
    BODY(t + 1, a1b, b1b, A0, B0);
  }
  #undef BODY

  int colb = n0 + wn * 64 + (lane & 15);
  int rowb = m0 + wm * 128 + (lane >> 4) * 4;
  #pragma unroll
  for (int fm = 0; fm < 8; fm++){
    #pragma unroll
    for (int fn = 0; fn < 4; fn++){
      f32x4 v = acc[fm][fn];
      int col = colb + fn * 16;
      #pragma unroll
      for (int rr = 0; rr < 4; rr++){
        int m = rowb + fm * 16 + rr;
        if constexpr (MODE == 0){
          Cb[(long)m * ldc + col] = f2bf(v[rr]);
        } else if constexpr (MODE == 1){
          if (m < cnt) Cb[(rbase + m) * (long)ldc + col] = f2bf(v[rr]);
        } else if constexpr (MODE == 2){
          if (m < cnt){
            int tok = lists[z * T_TOK + m];
            float pp = probs[z * T_TOK + m];
            atomicAdd(outp + (long)tok * ldc + col, pp * v[rr]);
          }
        } else {
          atomicAdd(outp + (long)m * ldc + col, svec[m] * v[rr]);
        }
      }
    }
  }
}

// distinct names so rocprof top-k localizes cost per mode
#define GEMM_ARGS const ushort_t* A, const ushort_t* Bt, const ushort_t* Bt2, ushort_t* Cb, \
    int K, int lda, int ldbt, int ldc, int mb, const int* counts, const int* bases, \
    const int* lists, const float* probs, const float* svec, float* outp, long bstride
#define GEMM_PASS A, Bt, Bt2, Cb, K, lda, ldbt, ldc, mb, counts, bases, lists, probs, svec, outp, bstride

__global__ __launch_bounds__(512) void g_shared_gi(GEMM_ARGS){ gemm4_body<0>(GEMM_PASS); }
__global__ __launch_bounds__(512) void g_shared_out(GEMM_ARGS){ gemm4_body<3>(GEMM_PASS); }
__global__ __launch_bounds__(512) void g_expert_gu(GEMM_ARGS){ gemm4_body<1>(GEMM_PASS); }
__global__ __launch_bounds__(512) void g_expert_out(GEMM_ARGS){ gemm4_body<2>(GEMM_PASS); }

extern "C" void kernel_launch(void* const* d_in, const int* in_sizes, int n_in,
                              void* d_out, int out_size, void* d_ws, size_t ws_size,
                              hipStream_t stream){
  const float* x    = (const float*)d_in[0];
  const float* rw   = (const float*)d_in[1];
  const float* wgu  = (const float*)d_in[2];
  const float* wout = (const float*)d_in[3];
  const float* wsg  = (const float*)d_in[4];
  const float* wsi  = (const float*)d_in[5];
  const float* wso  = (const float*)d_in[6];
  const float* sgw  = (const float*)d_in[7];

  float* out = (float*)d_out;
  float* logits = out + (size_t)T_TOK * H_DIM;

  char* w = (char*)d_ws;
  auto alloc = [&](size_t b){ char* p = w; w += (b + 255) & ~(size_t)255; return p; };
  ushort_t* xb     = (ushort_t*)alloc((size_t)T_TOK * H_DIM * 2);
  ushort_t* wgu_t  = (ushort_t*)alloc((size_t)NEXP * I2_DIM * H_DIM * 2);
  ushort_t* wout_t = (ushort_t*)alloc((size_t)NEXP * H_DIM * I_DIM * 2);
  ushort_t* wsg_t  = (ushort_t*)alloc((size_t)IS_DIM * H_DIM * 2);
  ushort_t* wsi_t  = (ushort_t*)alloc((size_t)IS_DIM * H_DIM * 2);
  ushort_t* wso_t  = (ushort_t*)alloc((size_t)H_DIM * IS_DIM * 2);
  ushort_t* sgr    = (ushort_t*)alloc((size_t)2 * T_TOK * IS_DIM * 2);
  ushort_t* sir    = sgr + (size_t)T_TOK * IS_DIM;
  ushort_t* gu     = (ushort_t*)alloc((size_t)MAXROWS * I2_DIM * 2);
  ushort_t* hid    = (ushort_t*)alloc((size_t)MAXROWS * I_DIM * 2);
  int*   counts = (int*)alloc(64);
  int*   bases  = (int*)alloc(64);
  int*   lists  = (int*)alloc((size_t)NEXP * T_TOK * 4);
  float* probs  = (float*)alloc((size_t)NEXP * T_TOK * 4);
  float* sgmul  = (float*)alloc((size_t)T_TOK * 4);

  hipMemsetAsync(counts, 0, 64, stream);
  hipMemsetAsync(out, 0, (size_t)T_TOK * H_DIM * sizeof(float), stream);

  cast_bf16_k<<<2048, 256, 0, stream>>>(x, xb);
  transpose_cast_k<<<dim3(I2_DIM/64, H_DIM/64, NEXP), 256, 0, stream>>>(wgu, wgu_t, H_DIM, I2_DIM);
  transpose_cast_k<<<dim3(H_DIM/64, I_DIM/64, NEXP), 256, 0, stream>>>(wout, wout_t, I_DIM, H_DIM);
  transpose_cast_k<<<dim3(IS_DIM/64, H_DIM/64, 1), 256, 0, stream>>>(wsg, wsg_t, H_DIM, IS_DIM);
  transpose_cast_k<<<dim3(IS_DIM/64, H_DIM/64, 1), 256, 0, stream>>>(wsi, wsi_t, H_DIM, IS_DIM);
  transpose_cast_k<<<dim3(H_DIM/64, IS_DIM/64, 1), 256, 0, stream>>>(wso, wso_t, IS_DIM, H_DIM);

  router_k<<<512, 256, 0, stream>>>(x, rw, sgw, logits, counts, lists, probs, sgmul);
  bases_k<<<1, 64, 0, stream>>>(counts, bases);

  // shared expert: gate & inter in one launch (z selects weight)
  g_shared_gi<<<dim3((T_TOK/256) * (IS_DIM/256), 1, 2), 512, 0, stream>>>(
      xb, wsg_t, wsi_t, sgr, H_DIM, H_DIM, H_DIM, IS_DIM, T_TOK/256,
      nullptr, nullptr, nullptr, nullptr, nullptr, nullptr, 0);
  swiglu_flat_k<<<(T_TOK * (IS_DIM/8)) / 256, 256, 0, stream>>>(sgr, sir);
  // shared out-projection, K-split x4, atomic accumulate into zeroed out
  g_shared_out<<<dim3((T_TOK/256) * (H_DIM/256), 4, 1), 512, 0, stream>>>(
      sgr, wso_t, nullptr, nullptr, IS_DIM, IS_DIM, IS_DIM, H_DIM, T_TOK/256,
      nullptr, nullptr, nullptr, nullptr, sgmul, out, 0);

  // sparse routed experts (atomic add on top of shared output)
  g_expert_gu<<<dim3((T_TOK/256) * (I2_DIM/256), 1, NEXP), 512, 0, stream>>>(
      xb, wgu_t, nullptr, gu, H_DIM, H_DIM, H_DIM, I2_DIM, T_TOK/256,
      counts, bases, lists, probs, nullptr, nullptr, (long)I2_DIM * H_DIM);
  swiglu_expert_k<<<((long)MAXROWS * (I_DIM/8)) / 256, 256, 0, stream>>>(gu, hid);
  g_expert_out<<<dim3((T_TOK/256) * (H_DIM/256), 1, NEXP), 512, 0, stream>>>(
      hid, wout_t, nullptr, nullptr, I_DIM, I_DIM, I_DIM, H_DIM, T_TOK/256,
      counts, bases, lists, probs, nullptr, out, (long)I_DIM * H_DIM);

  (void)in_sizes; (void)n_in; (void)out_size; (void)ws_size;
}

// Round 10
// 888.710 us; speedup vs baseline: 1.0442x; 1.0442x over previous
//
#include <hip/hip_runtime.h>
#include <math.h>

typedef __attribute__((ext_vector_type(2))) float f32x2;
typedef __attribute__((ext_vector_type(4))) float f32x4;
typedef __attribute__((ext_vector_type(4))) unsigned int u32x4;
typedef __attribute__((ext_vector_type(8))) unsigned short u16x8;
typedef __attribute__((ext_vector_type(8))) __bf16 bf16x8;
typedef unsigned short ushort_t;

#define H_DIM 2048
#define T_TOK 2048
#define NEXP 16
#define I_DIM 1408
#define I2_DIM 2816
#define IS_DIM 5632
#define MAXROWS 6144

static __device__ __forceinline__ unsigned short f2bf(float f){
  union { float f; unsigned u; } v; v.f = f;
  unsigned r = v.u + 0x7FFFu + ((v.u >> 16) & 1u);
  return (unsigned short)(r >> 16);
}
static __device__ __forceinline__ float bf2f(unsigned short h){
  union { unsigned u; float f; } v; v.u = ((unsigned)h) << 16;
  return v.f;
}
static __device__ __forceinline__ float silu_f(float x){ return x / (1.f + __expf(-x)); }

// async global->LDS, 16B/lane; LDS dest wave-uniform base, HW adds lane*16.
static __device__ __forceinline__ void gld16(const ushort_t* g, ushort_t* l){
  __builtin_amdgcn_global_load_lds(
      (const __attribute__((address_space(1))) unsigned int*)g,
      (__attribute__((address_space(3))) unsigned int*)l, 16, 0, 0);
}

// inline-asm ds_read_b128: opaque to LDS-DMA alias tracking (no forced vmcnt drain).
static __device__ __forceinline__ bf16x8 dsr128(unsigned byte_off){
  u32x4 r;
  asm volatile("ds_read_b128 %0, %1" : "=v"(r) : "v"(byte_off));
  return __builtin_bit_cast(bf16x8, r);
}
static __device__ __forceinline__ unsigned ldsaddr(const ushort_t* p){
  return (unsigned)(size_t)(const __attribute__((address_space(3))) ushort_t*)p;
}

// ---------------- cast x -> bf16 ----------------
__global__ void cast_bf16_k(const float* __restrict__ in, ushort_t* __restrict__ out){
  long i = ((long)blockIdx.x * 256 + threadIdx.x) * 8;
  f32x4 a = *(const f32x4*)&in[i];
  f32x4 b = *(const f32x4*)&in[i + 4];
  union { ushort_t s[8]; u32x4 v; } pk;
  #pragma unroll
  for (int j = 0; j < 4; j++){ pk.s[j] = f2bf(a[j]); pk.s[j+4] = f2bf(b[j]); }
  *(u32x4*)&out[i] = pk.v;
}

// ---------------- router ----------------
__global__ void router_k(const float* __restrict__ x, const float* __restrict__ rw,
                         const float* __restrict__ sgw, float* __restrict__ logits,
                         int* __restrict__ counts, int* __restrict__ lists,
                         float* __restrict__ probs, float* __restrict__ sgmul){
  int wid = threadIdx.x >> 6, lane = threadIdx.x & 63;
  int t = blockIdx.x * 4 + wid;
  const float* xr = x + (long)t * H_DIM;
  float acc[17];
  #pragma unroll
  for (int e = 0; e < 17; e++) acc[e] = 0.f;
  for (int h0 = lane * 4; h0 < H_DIM; h0 += 256){
    f32x4 xv = *(const f32x4*)&xr[h0];
    #pragma unroll
    for (int i = 0; i < 4; i++){
      float xs = xv[i];
      const float* wrow = rw + (long)(h0 + i) * NEXP;
      #pragma unroll
      for (int e = 0; e < 16; e++) acc[e] += xs * wrow[e];
      acc[16] += xs * sgw[h0 + i];
    }
  }
  #pragma unroll
  for (int e = 0; e < 17; e++)
    for (int off = 32; off >= 1; off >>= 1)
      acc[e] += __shfl_xor(acc[e], off);
  if (lane == 0){
    float* lo = logits + (long)t * NEXP;
    #pragma unroll
    for (int e = 0; e < 16; e++) lo[e] = acc[e];
    int e0 = 0;
    #pragma unroll
    for (int e = 1; e < 16; e++) if (acc[e] > acc[e0]) e0 = e;
    int e1 = (e0 == 0) ? 1 : 0;
    #pragma unroll
    for (int e = 0; e < 16; e++) if (e != e0 && acc[e] > acc[e1]) e1 = e;
    float d = acc[e1] - acc[e0];
    float ed = __expf(d);
    float p0 = 1.f / (1.f + ed);
    float p1 = ed / (1.f + ed);
    int pos0 = atomicAdd(&counts[e0], 1);
    lists[e0 * T_TOK + pos0] = t; probs[e0 * T_TOK + pos0] = p0;
    int pos1 = atomicAdd(&counts[e1], 1);
    lists[e1 * T_TOK + pos1] = t; probs[e1 * T_TOK + pos1] = p1;
    sgmul[t] = 1.f / (1.f + __expf(-acc[16]));
  }
}

// ---------------- padded prefix bases (128-aligned for 128-row tiles) ----------------
__global__ void bases_k(const int* __restrict__ counts, int* __restrict__ bases){
  if (threadIdx.x == 0){
    int r = 0;
    for (int e = 0; e < NEXP; e++){ bases[e] = r; r += (counts[e] + 127) & ~127; }
  }
}

// ---------------- SwiGLU elementwise ----------------
__global__ void swiglu_expert_k(const ushort_t* __restrict__ gu, ushort_t* __restrict__ hid){
  long qd = (long)blockIdx.x * 256 + threadIdx.x;
  long r = qd / (I_DIM / 8); int ic = (int)(qd % (I_DIM / 8)) * 8;
  const ushort_t* g = gu + r * I2_DIM + ic;
  u16x8 gv = *(const u16x8*)g;
  u16x8 uv = *(const u16x8*)(g + I_DIM);
  u16x8 ov;
  #pragma unroll
  for (int i = 0; i < 8; i++)
    ov[i] = f2bf(bf2f(uv[i]) * silu_f(bf2f(gv[i])));
  *(u16x8*)&hid[r * I_DIM + ic] = ov;
}

__global__ void swiglu_flat_k(ushort_t* __restrict__ sg, const ushort_t* __restrict__ si){
  long i = ((long)blockIdx.x * 256 + threadIdx.x) * 8;
  u16x8 g = *(const u16x8*)&sg[i];
  u16x8 s = *(const u16x8*)&si[i];
  u16x8 o;
  #pragma unroll
  for (int j = 0; j < 8; j++)
    o[j] = f2bf(bf2f(s[j]) * silu_f(bf2f(g[j])));
  *(u16x8*)&sg[i] = o;
}

// ======== 128x128 / BK=32 / 4-wave GEMM, fused fp32-B staging (no transpose pre-pass) ========
// A[M][K] bf16 via gld16 (R8 pattern). B native fp32 [K][N]: per-lane column-pair loads ->
// in-register cvt -> ds_write_b128 into [n][k] LDS tile. 2 static buffers, 1 barrier/K-step.
// Timeline per body t (reads cur, stages nxt): issue B-reg loads(t+1) + gld16 A(t+1)->nxt;
// asm ds_read frags(cur); lgkmcnt(0); MFMA; vmcnt(0); cvt+ds_write B(t+1)->nxt; barrier.
// Safety: all reads of a buffer complete (lgkmcnt(0) pre-MFMA) before the barrier that
// precedes any overwrite of it; B-writes are post-vmcnt, pre-barrier.
template<int MODE>
static __device__ __forceinline__ void gemm5_body(
    const ushort_t* __restrict__ A, const float* __restrict__ Bf,
    const float* __restrict__ Bf2, ushort_t* __restrict__ Cb,
    int K, int lda, int ldb, int ldc, int mb,
    const int* __restrict__ counts, const int* __restrict__ bases,
    const int* __restrict__ lists, const float* __restrict__ probs,
    const float* __restrict__ svec, float* __restrict__ outp, long bstride){
  int z = blockIdx.z;
  int cnt = T_TOK;
  const ushort_t* Ab = A;
  const float* Bb = Bf;
  long rbase = 0;
  if constexpr (MODE == 0){ if (z){ Bb = Bf2; Cb += (long)T_TOK * ldc; } }
  if constexpr (MODE == 1){ cnt = counts[z]; rbase = bases[z]; Bb += (long)z * bstride; }
  if constexpr (MODE == 2){ cnt = counts[z]; Ab += (long)bases[z] * lda; Bb += (long)z * bstride; }

  int kb = K / gridDim.y;          // MODE 3 K-split; others gridDim.y==1
  int kbase = blockIdx.y * kb;
  Ab += kbase;                     // A [M][K]
  Bb += (long)kbase * ldb;         // B [K][N]

  // bijective XCD-chunked swizzle (m204)
  int nwg = gridDim.x;
  int wgo = blockIdx.x;
  int q = nwg >> 3, r = nwg & 7;
  int xcd = wgo & 7, idx = wgo >> 3;
  int wg = (xcd < r ? xcd * (q + 1) : r * (q + 1) + (xcd - r) * q) + idx;
  int m0 = (wg % mb) * 128;
  if (m0 >= cnt) return;
  int n0 = (wg / mb) * 128;

  // 2 bufs x (A 128x32 + B 128x32) bf16 = 32 KiB
  __shared__ ushort_t A0[4096], B0[4096], A1[4096], B1[4096];

  int tid = threadIdx.x;
  int lane = tid & 63;
  int wv = tid >> 6;        // 4 waves
  int wm = wv >> 1;         // 0..1 -> 64 rows
  int wn = wv & 1;          // 0..1 -> 64 cols

  // ---- A staging (R8): wave wv stages rows [wv*32,+32), 2 gld16; source pre-swizzled.
  int srow = lane >> 2;
  int sslot = ((lane & 3) ^ (srow & 3)) * 8;
  long aoff[2];
  #pragma unroll
  for (int c = 0; c < 2; c++){
    int mr = wv * 32 + c * 16 + srow;
    int grow;
    if constexpr (MODE == 1){
      int j = m0 + mr; if (j >= cnt) j = cnt - 1;
      grow = lists[z * T_TOK + j];
    } else {
      grow = m0 + mr;
    }
    aoff[c] = (long)grow * lda + sslot;
  }

  // ---- B staging: lane owns n-pair (2*lane, 2*lane+1); wave owns k rows [wv*8, wv*8+8).
  const float* bB = Bb + (long)(wv * 8) * ldb + n0 + 2 * lane;
  // LDS write: row n (32 elems, 64B), slot = (wv ^ ((n>>1)&3)) = wv ^ (lane&3)
  int bws = (2 * lane) * 32 + (wv ^ (lane & 3)) * 8;   // elem offset for n=2*lane
  f32x2 bl[8];

  f32x4 zero = {0.f, 0.f, 0.f, 0.f};
  f32x4 acc[4][4];
  #pragma unroll
  for (int i = 0; i < 4; i++)
    #pragma unroll
    for (int j = 0; j < 4; j++) acc[i][j] = zero;

  // fragment read offsets (bytes), row stride 64 B:
  // A slot XOR (fr&3) [matches gld16 source pre-swizzle]; B slot XOR ((fr>>1)&3).
  int fr = lane & 15;
  int kg = lane >> 4;
  unsigned aro = (unsigned)((wm * 64 + fr) * 64) + (unsigned)((kg ^ (fr & 3)) << 4);
  unsigned bro = (unsigned)((wn * 64 + fr) * 64) + (unsigned)((kg ^ ((fr >> 1) & 3)) << 4);
  unsigned a0b = ldsaddr(A0), b0b = ldsaddr(B0);
  unsigned a1b = ldsaddr(A1), b1b = ldsaddr(B1);

  int nt = kb >> 5;   // 64 / 44 everywhere (even)

  // ---- prologue: stage tile 0 into A0/B0
  #pragma unroll
  for (int j = 0; j < 8; j++) bl[j] = *(const f32x2*)(bB + (long)j * ldb);
  gld16(Ab + aoff[0], A0 + wv * 1024);
  gld16(Ab + aoff[1], A0 + wv * 1024 + 512);
  asm volatile("s_waitcnt vmcnt(0)" ::: "memory");
  {
    bf16x8 c0, c1;
    #pragma unroll
    for (int j = 0; j < 8; j++){ c0[j] = (__bf16)bl[j][0]; c1[j] = (__bf16)bl[j][1]; }
    *(bf16x8*)(B0 + bws) = c0;
    *(bf16x8*)(B0 + bws + 32) = c1;
  }
  __syncthreads();

  #define BODY(T, CAb, CBb, NAp, NBp)                                            \
  {                                                                              \
    bool more = (T) + 1 < nt;                                                    \
    if (more){                                                                   \
      long t32 = (long)((T) + 1) * 32;                                           \
      const float* bp = bB + t32 * ldb;                                          \
      _Pragma("unroll")                                                          \
      for (int j = 0; j < 8; j++) bl[j] = *(const f32x2*)(bp + (long)j * ldb);   \
      gld16(Ab + aoff[0] + t32, NAp + wv * 1024);                                \
      gld16(Ab + aoff[1] + t32, NAp + wv * 1024 + 512);                          \
    }                                                                            \
    __builtin_amdgcn_sched_barrier(0);                                           \
    bf16x8 af[4], bg[4];                                                         \
    _Pragma("unroll")                                                            \
    for (int f = 0; f < 4; f++){                                                 \
      af[f] = dsr128(CAb + aro + f * 1024u);                                     \
      bg[f] = dsr128(CBb + bro + f * 1024u);                                     \
    }                                                                            \
    asm volatile("s_waitcnt lgkmcnt(0)" ::: "memory");                           \
    __builtin_amdgcn_sched_barrier(0);                                           \
    __builtin_amdgcn_s_setprio(1);                                               \
    _Pragma("unroll")                                                            \
    for (int fm = 0; fm < 4; fm++)                                               \
      _Pragma("unroll")                                                          \
      for (int fn = 0; fn < 4; fn++)                                             \
        acc[fm][fn] = __builtin_amdgcn_mfma_f32_16x16x32_bf16(af[fm], bg[fn],    \
                                                              acc[fm][fn], 0, 0, 0); \
    __builtin_amdgcn_s_setprio(0);                                               \
    if (more){                                                                   \
      asm volatile("s_waitcnt vmcnt(0)" ::: "memory");                           \
      __builtin_amdgcn_sched_barrier(0);                                         \
      bf16x8 c0, c1;                                                             \
      _Pragma("unroll")                                                          \
      for (int j = 0; j < 8; j++){ c0[j] = (__bf16)bl[j][0]; c1[j] = (__bf16)bl[j][1]; } \
      *(bf16x8*)(NBp + bws) = c0;                                                \
      *(bf16x8*)(NBp + bws + 32) = c1;                                           \
    }                                                                            \
    __syncthreads();                                                             \
  }

  for (int t = 0; t < nt; t += 2){
    BODY(t,     a0b, b0b, A1, B1);
    BODY(t + 1, a1b, b1b, A0, B0);
  }
  #undef BODY

  int colb = n0 + wn * 64 + (lane & 15);
  int rowb = m0 + wm * 64 + (lane >> 4) * 4;
  #pragma unroll
  for (int fm = 0; fm < 4; fm++){
    #pragma unroll
    for (int fn = 0; fn < 4; fn++){
      f32x4 v = acc[fm][fn];
      int col = colb + fn * 16;
      #pragma unroll
      for (int rr = 0; rr < 4; rr++){
        int m = rowb + fm * 16 + rr;
        if constexpr (MODE == 0){
          Cb[(long)m * ldc + col] = f2bf(v[rr]);
        } else if constexpr (MODE == 1){
          if (m < cnt) Cb[(rbase + m) * (long)ldc + col] = f2bf(v[rr]);
        } else if constexpr (MODE == 2){
          if (m < cnt){
            int tok = lists[z * T_TOK + m];
            float pp = probs[z * T_TOK + m];
            atomicAdd(outp + (long)tok * ldc + col, pp * v[rr]);
          }
        } else {
          atomicAdd(outp + (long)m * ldc + col, svec[m] * v[rr]);
        }
      }
    }
  }
}

// distinct names so rocprof top-k localizes cost per mode
#define GEMM_ARGS const ushort_t* A, const float* Bf, const float* Bf2, ushort_t* Cb, \
    int K, int lda, int ldb, int ldc, int mb, const int* counts, const int* bases, \
    const int* lists, const float* probs, const float* svec, float* outp, long bstride
#define GEMM_PASS A, Bf, Bf2, Cb, K, lda, ldb, ldc, mb, counts, bases, lists, probs, svec, outp, bstride

__global__ __launch_bounds__(256) void g_shared_gi(GEMM_ARGS){ gemm5_body<0>(GEMM_PASS); }
__global__ __launch_bounds__(256) void g_shared_out(GEMM_ARGS){ gemm5_body<3>(GEMM_PASS); }
__global__ __launch_bounds__(256) void g_expert_gu(GEMM_ARGS){ gemm5_body<1>(GEMM_PASS); }
__global__ __launch_bounds__(256) void g_expert_out(GEMM_ARGS){ gemm5_body<2>(GEMM_PASS); }

extern "C" void kernel_launch(void* const* d_in, const int* in_sizes, int n_in,
                              void* d_out, int out_size, void* d_ws, size_t ws_size,
                              hipStream_t stream){
  const float* x    = (const float*)d_in[0];
  const float* rw   = (const float*)d_in[1];
  const float* wgu  = (const float*)d_in[2];
  const float* wout = (const float*)d_in[3];
  const float* wsg  = (const float*)d_in[4];
  const float* wsi  = (const float*)d_in[5];
  const float* wso  = (const float*)d_in[6];
  const float* sgw  = (const float*)d_in[7];

  float* out = (float*)d_out;
  float* logits = out + (size_t)T_TOK * H_DIM;

  char* w = (char*)d_ws;
  auto alloc = [&](size_t b){ char* p = w; w += (b + 255) & ~(size_t)255; return p; };
  ushort_t* xb  = (ushort_t*)alloc((size_t)T_TOK * H_DIM * 2);
  ushort_t* sgr = (ushort_t*)alloc((size_t)2 * T_TOK * IS_DIM * 2);
  ushort_t* sir = sgr + (size_t)T_TOK * IS_DIM;
  ushort_t* gu  = (ushort_t*)alloc((size_t)MAXROWS * I2_DIM * 2);
  ushort_t* hid = (ushort_t*)alloc((size_t)MAXROWS * I_DIM * 2);
  int*   counts = (int*)alloc(64);
  int*   bases  = (int*)alloc(64);
  int*   lists  = (int*)alloc((size_t)NEXP * T_TOK * 4);
  float* probs  = (float*)alloc((size_t)NEXP * T_TOK * 4);
  float* sgmul  = (float*)alloc((size_t)T_TOK * 4);

  hipMemsetAsync(counts, 0, 64, stream);
  hipMemsetAsync(out, 0, (size_t)T_TOK * H_DIM * sizeof(float), stream);

  cast_bf16_k<<<2048, 256, 0, stream>>>(x, xb);
  router_k<<<512, 256, 0, stream>>>(x, rw, sgw, logits, counts, lists, probs, sgmul);
  bases_k<<<1, 64, 0, stream>>>(counts, bases);

  // shared expert: gate & inter in one launch (z selects weight; B fp32 native [K][N])
  g_shared_gi<<<dim3((T_TOK/128) * (IS_DIM/128), 1, 2), 256, 0, stream>>>(
      xb, wsg, wsi, sgr, H_DIM, H_DIM, IS_DIM, IS_DIM, T_TOK/128,
      nullptr, nullptr, nullptr, nullptr, nullptr, nullptr, 0);
  swiglu_flat_k<<<(T_TOK * (IS_DIM/8)) / 256, 256, 0, stream>>>(sgr, sir);
  // shared out-projection, K-split x4, atomic accumulate into zeroed out
  g_shared_out<<<dim3((T_TOK/128) * (H_DIM/128), 4, 1), 256, 0, stream>>>(
      sgr, wso, nullptr, nullptr, IS_DIM, IS_DIM, H_DIM, H_DIM, T_TOK/128,
      nullptr, nullptr, nullptr, nullptr, sgmul, out, 0);

  // sparse routed experts (atomic add on top of shared output)
  g_expert_gu<<<dim3((T_TOK/128) * (I2_DIM/128), 1, NEXP), 256, 0, stream>>>(
      xb, wgu, nullptr, gu, H_DIM, H_DIM, I2_DIM, I2_DIM, T_TOK/128,
      counts, bases, lists, probs, nullptr, nullptr, (long)H_DIM * I2_DIM);
  swiglu_expert_k<<<((long)MAXROWS * (I_DIM/8)) / 256, 256, 0, stream>>>(gu, hid);
  g_expert_out<<<dim3((T_TOK/128) * (H_DIM/128), 1, NEXP), 256, 0, stream>>>(
      hid, wout, nullptr, nullptr, I_DIM, I_DIM, H_DIM, H_DIM, T_TOK/128,
      counts, bases, lists, probs, nullptr, out, (long)I_DIM * H_DIM);

  (void)in_sizes; (void)n_in; (void)out_size; (void)ws_size;
}

// Round 11
// 829.719 us; speedup vs baseline: 1.1185x; 1.0711x over previous
//
#include <hip/hip_runtime.h>
#include <math.h>

typedef __attribute__((ext_vector_type(4))) float f32x4;
typedef __attribute__((ext_vector_type(4))) unsigned int u32x4;
typedef __attribute__((ext_vector_type(8))) unsigned short u16x8;
typedef __attribute__((ext_vector_type(8))) __bf16 bf16x8;
typedef unsigned short ushort_t;

#define H_DIM 2048
#define T_TOK 2048
#define NEXP 16
#define I_DIM 1408
#define I2_DIM 2816
#define IS_DIM 5632
#define MAXROWS 6144

static __device__ __forceinline__ unsigned short f2bf(float f){
  union { float f; unsigned u; } v; v.f = f;
  unsigned r = v.u + 0x7FFFu + ((v.u >> 16) & 1u);
  return (unsigned short)(r >> 16);
}
static __device__ __forceinline__ float bf2f(unsigned short h){
  union { unsigned u; float f; } v; v.u = ((unsigned)h) << 16;
  return v.f;
}
static __device__ __forceinline__ float silu_f(float x){ return x / (1.f + __expf(-x)); }

// async global->LDS, 16B/lane; LDS dest wave-uniform base, HW adds lane*16.
static __device__ __forceinline__ void gld16(const ushort_t* g, ushort_t* l){
  __builtin_amdgcn_global_load_lds(
      (const __attribute__((address_space(1))) unsigned int*)g,
      (__attribute__((address_space(3))) unsigned int*)l, 16, 0, 0);
}

// inline-asm ds_read_b128: opaque to LDS-DMA alias tracking (no forced vmcnt drain).
static __device__ __forceinline__ bf16x8 dsr128(unsigned byte_off){
  u32x4 r;
  asm volatile("ds_read_b128 %0, %1" : "=v"(r) : "v"(byte_off));
  return __builtin_bit_cast(bf16x8, r);
}

// ---------------- cast x -> bf16 ----------------
__global__ void cast_bf16_k(const float* __restrict__ in, ushort_t* __restrict__ out){
  long i = ((long)blockIdx.x * 256 + threadIdx.x) * 8;
  f32x4 a = *(const f32x4*)&in[i];
  f32x4 b = *(const f32x4*)&in[i + 4];
  union { ushort_t s[8]; u32x4 v; } pk;
  #pragma unroll
  for (int j = 0; j < 4; j++){ pk.s[j] = f2bf(a[j]); pk.s[j+4] = f2bf(b[j]); }
  *(u32x4*)&out[i] = pk.v;
}

// ------- transpose + cast: in[z][K][N] fp32 -> out[z][N][K] bf16, 64x64 tiles ------
__global__ void transpose_cast_k(const float* __restrict__ in, ushort_t* __restrict__ out,
                                 int K, int N){
  long zo = (long)blockIdx.z * K * N;
  in += zo; out += zo;
  __shared__ float tl[64][65];
  int n0 = blockIdx.x * 64, k0 = blockIdx.y * 64;
  int tid = threadIdx.x;           // 256
  int lr = tid >> 2;               // source row (k)
  int lv = (tid & 3) * 4;
  #pragma unroll
  for (int j = 0; j < 4; j++){
    int col = lv + j * 16;
    f32x4 v = *(const f32x4*)&in[(long)(k0 + lr) * N + n0 + col];
    tl[lr][col + 0] = v[0]; tl[lr][col + 1] = v[1];
    tl[lr][col + 2] = v[2]; tl[lr][col + 3] = v[3];
  }
  __syncthreads();
  int nl = tid >> 3;
  int kc = (tid & 7) * 8;
  #pragma unroll
  for (int it = 0; it < 2; it++){
    int n = nl + it * 32;
    union { ushort_t s[8]; u32x4 v; } pk;
    #pragma unroll
    for (int j = 0; j < 8; j++) pk.s[j] = f2bf(tl[kc + j][n]);
    *(u32x4*)&out[(long)(n0 + n) * K + k0 + kc] = pk.v;
  }
}

// ---------------- router ----------------
__global__ void router_k(const float* __restrict__ x, const float* __restrict__ rw,
                         const float* __restrict__ sgw, float* __restrict__ logits,
                         int* __restrict__ counts, int* __restrict__ lists,
                         float* __restrict__ probs, float* __restrict__ sgmul){
  int wid = threadIdx.x >> 6, lane = threadIdx.x & 63;
  int t = blockIdx.x * 4 + wid;
  const float* xr = x + (long)t * H_DIM;
  float acc[17];
  #pragma unroll
  for (int e = 0; e < 17; e++) acc[e] = 0.f;
  for (int h0 = lane * 4; h0 < H_DIM; h0 += 256){
    f32x4 xv = *(const f32x4*)&xr[h0];
    #pragma unroll
    for (int i = 0; i < 4; i++){
      float xs = xv[i];
      const float* wrow = rw + (long)(h0 + i) * NEXP;
      #pragma unroll
      for (int e = 0; e < 16; e++) acc[e] += xs * wrow[e];
      acc[16] += xs * sgw[h0 + i];
    }
  }
  #pragma unroll
  for (int e = 0; e < 17; e++)
    for (int off = 32; off >= 1; off >>= 1)
      acc[e] += __shfl_xor(acc[e], off);
  if (lane == 0){
    float* lo = logits + (long)t * NEXP;
    #pragma unroll
    for (int e = 0; e < 16; e++) lo[e] = acc[e];
    int e0 = 0;
    #pragma unroll
    for (int e = 1; e < 16; e++) if (acc[e] > acc[e0]) e0 = e;
    int e1 = (e0 == 0) ? 1 : 0;
    #pragma unroll
    for (int e = 0; e < 16; e++) if (e != e0 && acc[e] > acc[e1]) e1 = e;
    float d = acc[e1] - acc[e0];
    float ed = __expf(d);
    float p0 = 1.f / (1.f + ed);
    float p1 = ed / (1.f + ed);
    int pos0 = atomicAdd(&counts[e0], 1);
    lists[e0 * T_TOK + pos0] = t; probs[e0 * T_TOK + pos0] = p0;
    int pos1 = atomicAdd(&counts[e1], 1);
    lists[e1 * T_TOK + pos1] = t; probs[e1 * T_TOK + pos1] = p1;
    sgmul[t] = 1.f / (1.f + __expf(-acc[16]));
  }
}

// ---------------- padded prefix bases (128-aligned) ----------------
__global__ void bases_k(const int* __restrict__ counts, int* __restrict__ bases){
  if (threadIdx.x == 0){
    int r = 0;
    for (int e = 0; e < NEXP; e++){ bases[e] = r; r += (counts[e] + 127) & ~127; }
  }
}

// ---------------- SwiGLU elementwise ----------------
__global__ void swiglu_expert_k(const ushort_t* __restrict__ gu, ushort_t* __restrict__ hid){
  long qd = (long)blockIdx.x * 256 + threadIdx.x;
  long r = qd / (I_DIM / 8); int ic = (int)(qd % (I_DIM / 8)) * 8;
  const ushort_t* g = gu + r * I2_DIM + ic;
  u16x8 gv = *(const u16x8*)g;
  u16x8 uv = *(const u16x8*)(g + I_DIM);
  u16x8 ov;
  #pragma unroll
  for (int i = 0; i < 8; i++)
    ov[i] = f2bf(bf2f(uv[i]) * silu_f(bf2f(gv[i])));
  *(u16x8*)&hid[r * I_DIM + ic] = ov;
}

__global__ void swiglu_flat_k(ushort_t* __restrict__ sg, const ushort_t* __restrict__ si){
  long i = ((long)blockIdx.x * 256 + threadIdx.x) * 8;
  u16x8 g = *(const u16x8*)&sg[i];
  u16x8 s = *(const u16x8*)&si[i];
  u16x8 o;
  #pragma unroll
  for (int j = 0; j < 8; j++)
    o[j] = f2bf(bf2f(s[j]) * silu_f(bf2f(g[j])));
  *(u16x8*)&sg[i] = o;
}

// ======== R8 GEMM core: 128x128 / BK=32 / 4 waves, 3-buffer vmcnt(4), asm ds_read ========
// emode: 0 = bf16 store to Cb; 1 = bf16 masked store at rbase (expert up);
//        2 = atomicAdd scprob*val scattered via sclist (expert down);
//        3 = atomicAdd svec[m]*val (shared down).
static __device__ __forceinline__ void gemm_core(
    const ushort_t* __restrict__ Ab, int lda,
    const ushort_t* __restrict__ Bb, int ldbt,
    int kb, int m0, int n0, int cnt,
    const int* __restrict__ gather,      // null = dense A rows
    int emode, ushort_t* __restrict__ Cb, int ldc, long rbase,
    const int* __restrict__ sclist, const float* __restrict__ scprob,
    const float* __restrict__ svec, float* __restrict__ outp){
  __shared__ ushort_t lds[3 * 8192];     // 3 bufs x (A 4096 + B 4096) elems = 48 KiB
  unsigned lbase = (unsigned)(size_t)(__attribute__((address_space(3))) ushort_t*)lds;

  int tid = threadIdx.x;
  int lane = tid & 63;
  int wv = tid >> 6;        // 4 waves
  int wm = wv >> 1;
  int wn = wv & 1;

  int srow = lane >> 2;
  int sslot = ((lane & 3) ^ (srow & 3)) * 8;
  long aoff[2], boff[2];
  #pragma unroll
  for (int c = 0; c < 2; c++){
    int mr = wv * 32 + c * 16 + srow;
    int grow;
    if (gather){
      int j = m0 + mr; if (j >= cnt) j = cnt - 1;
      grow = gather[j];
    } else {
      grow = m0 + mr;
    }
    aoff[c] = (long)grow * lda + sslot;
    boff[c] = (long)(n0 + mr) * ldbt + sslot;
  }

  auto stage = [&](int t, int buf){
    long ko = (long)t * 32;
    ushort_t* dA = lds + buf * 8192 + wv * 1024;
    ushort_t* dB = dA + 4096;
    gld16(Ab + aoff[0] + ko, dA);
    gld16(Ab + aoff[1] + ko, dA + 512);
    gld16(Bb + boff[0] + ko, dB);
    gld16(Bb + boff[1] + ko, dB + 512);
  };

  f32x4 zero = {0.f, 0.f, 0.f, 0.f};
  f32x4 acc[4][4];
  #pragma unroll
  for (int i = 0; i < 4; i++)
    #pragma unroll
    for (int j = 0; j < 4; j++) acc[i][j] = zero;

  int fr = lane & 15;
  int kg = lane >> 4;
  unsigned ps = (unsigned)((kg ^ (fr & 3)) << 4);
  unsigned aoffb = (unsigned)((wm * 64 + fr) * 64) + ps;
  unsigned boffb = 8192u + (unsigned)((wn * 64 + fr) * 64) + ps;

  int nt = kb >> 5;
  stage(0, 0);
  __builtin_amdgcn_sched_barrier(0);
  stage(1, 1);

  int rb = 0, sb = 2;
  for (int t = 0; t < nt; t++){
    if (t + 2 < nt) asm volatile("s_waitcnt vmcnt(4)" ::: "memory");
    else            asm volatile("s_waitcnt vmcnt(0)" ::: "memory");
    __builtin_amdgcn_s_barrier();
    __builtin_amdgcn_sched_barrier(0);
    unsigned bufb = lbase + (unsigned)rb * 16384u;
    bf16x8 af[4], bg[4];
    #pragma unroll
    for (int f = 0; f < 4; f++){
      af[f] = dsr128(bufb + aoffb + f * 1024u);
      bg[f] = dsr128(bufb + boffb + f * 1024u);
    }
    __builtin_amdgcn_sched_barrier(0);
    if (t + 2 < nt) stage(t + 2, sb);
    asm volatile("s_waitcnt lgkmcnt(0)" ::: "memory");
    __builtin_amdgcn_sched_barrier(0);
    __builtin_amdgcn_s_setprio(1);
    #pragma unroll
    for (int fm = 0; fm < 4; fm++)
      #pragma unroll
      for (int fn = 0; fn < 4; fn++)
        acc[fm][fn] = __builtin_amdgcn_mfma_f32_16x16x32_bf16(af[fm], bg[fn], acc[fm][fn], 0, 0, 0);
    __builtin_amdgcn_s_setprio(0);
    rb = (rb == 2) ? 0 : rb + 1;
    sb = (sb == 2) ? 0 : sb + 1;
  }

  int colb = n0 + wn * 64 + (lane & 15);
  int rowb = m0 + wm * 64 + (lane >> 4) * 4;
  #pragma unroll
  for (int fm = 0; fm < 4; fm++){
    #pragma unroll
    for (int fn = 0; fn < 4; fn++){
      f32x4 v = acc[fm][fn];
      int col = colb + fn * 16;
      #pragma unroll
      for (int rr = 0; rr < 4; rr++){
        int m = rowb + fm * 16 + rr;
        if (emode == 0){
          Cb[(long)m * ldc + col] = f2bf(v[rr]);
        } else if (emode == 1){
          if (m < cnt) Cb[(rbase + m) * (long)ldc + col] = f2bf(v[rr]);
        } else if (emode == 2){
          if (m < cnt){
            int tok = sclist[m];
            atomicAdd(outp + (long)tok * ldc + col, scprob[m] * v[rr]);
          }
        } else {
          atomicAdd(outp + (long)m * ldc + col, svec[m] * v[rr]);
        }
      }
    }
  }
}

// bijective XCD-chunked swizzle (m204), m-fastest decode (mb m-blocks).
static __device__ __forceinline__ int swz_wg(){
  int nwg = gridDim.x;
  int wgo = blockIdx.x;
  int q = nwg >> 3, r = nwg & 7;
  int xcd = wgo & 7, idx = wgo >> 3;
  return (xcd < r ? xcd * (q + 1) : r * (q + 1) + (xcd - r) * q) + idx;
}

// ---- merged "up" GEMMs: z<2 shared gate/inter (dense, store slab); z>=2 expert gate_up ----
__global__ __launch_bounds__(256) void g_up(
    const ushort_t* xb, const ushort_t* wsg_t, const ushort_t* wsi_t,
    const ushort_t* wgu_t, ushort_t* sgr, ushort_t* gu,
    const int* counts, const int* bases, const int* lists){
  int z = blockIdx.z;
  int wg = swz_wg();
  int mblk = wg & 15, nblk = wg >> 4;     // gridDim.x = 704 = 16 m x 44 n
  int m0 = mblk * 128, n0 = nblk * 128;
  if (z < 2){
    gemm_core(xb, H_DIM, (z ? wsi_t : wsg_t), H_DIM, H_DIM, m0, n0, T_TOK,
              nullptr, 0, sgr + (size_t)z * T_TOK * IS_DIM, IS_DIM, 0,
              nullptr, nullptr, nullptr, nullptr);
  } else {
    int e = z - 2;
    if (nblk >= I2_DIM / 128) return;
    int cnt = counts[e];
    if (m0 >= cnt) return;
    gemm_core(xb, H_DIM, wgu_t + (size_t)e * I2_DIM * H_DIM, H_DIM, H_DIM,
              m0, n0, cnt, lists + e * T_TOK,
              1, gu, I2_DIM, bases[e],
              nullptr, nullptr, nullptr, nullptr);
  }
}

// ---- merged "down" GEMMs: z<2 shared out (K-split halves, svec); z>=2 expert out ----
__global__ __launch_bounds__(256) void g_down(
    const ushort_t* sgr, const ushort_t* hid,
    const ushort_t* wso_t, const ushort_t* wout_t,
    const int* counts, const int* bases, const int* lists,
    const float* probs, const float* sgmul, float* out){
  int z = blockIdx.z;
  int wg = swz_wg();
  int mblk = wg & 15, nblk = wg >> 4;     // gridDim.x = 256 = 16 m x 16 n
  int m0 = mblk * 128, n0 = nblk * 128;
  if (z < 2){
    // K-split: z half of K=IS_DIM
    gemm_core(sgr + z * (IS_DIM / 2), IS_DIM, wso_t + z * (IS_DIM / 2), IS_DIM,
              IS_DIM / 2, m0, n0, T_TOK, nullptr,
              3, nullptr, H_DIM, 0,
              nullptr, nullptr, sgmul, out);
  } else {
    int e = z - 2;
    int cnt = counts[e];
    if (m0 >= cnt) return;
    gemm_core(hid + (size_t)bases[e] * I_DIM, I_DIM,
              wout_t + (size_t)e * H_DIM * I_DIM, I_DIM,
              I_DIM, m0, n0, cnt, nullptr,
              2, nullptr, H_DIM, 0,
              lists + e * T_TOK, probs + e * T_TOK, nullptr, out);
  }
}

extern "C" void kernel_launch(void* const* d_in, const int* in_sizes, int n_in,
                              void* d_out, int out_size, void* d_ws, size_t ws_size,
                              hipStream_t stream){
  const float* x    = (const float*)d_in[0];
  const float* rw   = (const float*)d_in[1];
  const float* wgu  = (const float*)d_in[2];
  const float* wout = (const float*)d_in[3];
  const float* wsg  = (const float*)d_in[4];
  const float* wsi  = (const float*)d_in[5];
  const float* wso  = (const float*)d_in[6];
  const float* sgw  = (const float*)d_in[7];

  float* out = (float*)d_out;
  float* logits = out + (size_t)T_TOK * H_DIM;

  char* w = (char*)d_ws;
  auto alloc = [&](size_t b){ char* p = w; w += (b + 255) & ~(size_t)255; return p; };
  ushort_t* xb     = (ushort_t*)alloc((size_t)T_TOK * H_DIM * 2);
  ushort_t* wgu_t  = (ushort_t*)alloc((size_t)NEXP * I2_DIM * H_DIM * 2);
  ushort_t* wout_t = (ushort_t*)alloc((size_t)NEXP * H_DIM * I_DIM * 2);
  ushort_t* wsg_t  = (ushort_t*)alloc((size_t)IS_DIM * H_DIM * 2);
  ushort_t* wsi_t  = (ushort_t*)alloc((size_t)IS_DIM * H_DIM * 2);
  ushort_t* wso_t  = (ushort_t*)alloc((size_t)H_DIM * IS_DIM * 2);
  ushort_t* sgr    = (ushort_t*)alloc((size_t)2 * T_TOK * IS_DIM * 2);
  ushort_t* sir    = sgr + (size_t)T_TOK * IS_DIM;
  ushort_t* gu     = (ushort_t*)alloc((size_t)MAXROWS * I2_DIM * 2);
  ushort_t* hid    = (ushort_t*)alloc((size_t)MAXROWS * I_DIM * 2);
  int*   counts = (int*)alloc(64);
  int*   bases  = (int*)alloc(64);
  int*   lists  = (int*)alloc((size_t)NEXP * T_TOK * 4);
  float* probs  = (float*)alloc((size_t)NEXP * T_TOK * 4);
  float* sgmul  = (float*)alloc((size_t)T_TOK * 4);

  hipMemsetAsync(counts, 0, 64, stream);
  hipMemsetAsync(out, 0, (size_t)T_TOK * H_DIM * sizeof(float), stream);

  cast_bf16_k<<<2048, 256, 0, stream>>>(x, xb);
  transpose_cast_k<<<dim3(I2_DIM/64, H_DIM/64, NEXP), 256, 0, stream>>>(wgu, wgu_t, H_DIM, I2_DIM);
  transpose_cast_k<<<dim3(H_DIM/64, I_DIM/64, NEXP), 256, 0, stream>>>(wout, wout_t, I_DIM, H_DIM);
  transpose_cast_k<<<dim3(IS_DIM/64, H_DIM/64, 1), 256, 0, stream>>>(wsg, wsg_t, H_DIM, IS_DIM);
  transpose_cast_k<<<dim3(IS_DIM/64, H_DIM/64, 1), 256, 0, stream>>>(wsi, wsi_t, H_DIM, IS_DIM);
  transpose_cast_k<<<dim3(H_DIM/64, IS_DIM/64, 1), 256, 0, stream>>>(wso, wso_t, IS_DIM, H_DIM);

  router_k<<<512, 256, 0, stream>>>(x, rw, sgw, logits, counts, lists, probs, sgmul);
  bases_k<<<1, 64, 0, stream>>>(counts, bases);

  // merged up-projections: shared gate+inter (z 0,1) + 16 expert gate_up (z 2..17)
  g_up<<<dim3(16 * (IS_DIM/128), 1, 2 + NEXP), 256, 0, stream>>>(
      xb, wsg_t, wsi_t, wgu_t, sgr, gu, counts, bases, lists);

  swiglu_flat_k<<<(T_TOK * (IS_DIM/8)) / 256, 256, 0, stream>>>(sgr, sir);
  swiglu_expert_k<<<((long)MAXROWS * (I_DIM/8)) / 256, 256, 0, stream>>>(gu, hid);

  // merged down-projections: shared out K-split (z 0,1) + 16 expert out (z 2..17)
  g_down<<<dim3(16 * (H_DIM/128), 1, 2 + NEXP), 256, 0, stream>>>(
      sgr, hid, wso_t, wout_t, counts, bases, lists, probs, sgmul, out);

  (void)in_sizes; (void)n_in; (void)out_size; (void)ws_size;
}